// Round 9
// baseline (78.259 us; speedup 1.0000x reference)
//
#include <hip/hip_runtime.h>
#include <stdint.h>

#define NN 2048
#define KK 20
#define NSLICE 8   // L*B = 2*4
#define NROWS (NSLICE * NN)        // 16384
#define NBOOST (NROWS * KK)        // 327680

typedef float vfloat4 __attribute__((ext_vector_type(4)));
typedef unsigned long long u64;

// Wave-wide max of a nonnegative int, result broadcast (SGPR). Pure VALU DPP.
__device__ __forceinline__ int wave_max_i32(int v) {
    int t;
    t = __builtin_amdgcn_update_dpp(0, v, 0x111, 0xf, 0xf, true);  // row_shr:1
    v = (v > t) ? v : t;
    t = __builtin_amdgcn_update_dpp(0, v, 0x112, 0xf, 0xf, true);  // row_shr:2
    v = (v > t) ? v : t;
    t = __builtin_amdgcn_update_dpp(0, v, 0x114, 0xf, 0xf, true);  // row_shr:4
    v = (v > t) ? v : t;
    t = __builtin_amdgcn_update_dpp(0, v, 0x118, 0xf, 0xf, true);  // row_shr:8
    v = (v > t) ? v : t;
    t = __builtin_amdgcn_update_dpp(v, v, 0x142, 0xa, 0xf, false); // row_bcast:15
    v = (v > t) ? v : t;
    t = __builtin_amdgcn_update_dpp(v, v, 0x143, 0xc, 0xf, false); // row_bcast:31
    v = (v > t) ? v : t;
    return __builtin_amdgcn_readlane(v, 63);
}

// Branch-free insert of k into sorted (m1 >= m2 >= m3 >= m4), 64-bit keys.
__device__ __forceinline__ void insert4(u64 k, u64& m1, u64& m2, u64& m3, u64& m4) {
    const bool c1 = k > m1, c2 = k > m2, c3 = k > m3, c4 = k > m4;
    m4 = c4 ? (c3 ? m3 : k) : m4;   // uses old m3
    m3 = c3 ? (c2 ? m2 : k) : m3;   // uses old m2
    m2 = c2 ? (c1 ? m1 : k) : m2;   // uses old m1
    m1 = c1 ? k : m1;
}

// Issue one tile pair via volatile asm (order-pinned among volatile asms).
#define ISSUE(slot, t) do {                                                  \
    asm volatile("global_load_dwordx4 %0, %1, off"                           \
                 : "=v"(av##slot) : "v"(arow + (t) * 256 + lane4));          \
    asm volatile("global_load_dwordx4 %0, %1, off"                           \
                 : "=v"(nv##slot) : "v"(nrow + (t) * 256 + lane4));          \
} while (0)

// Wait for tile t's pair (counted: younger loads + NT stores in the FIFO),
// fence the scheduler (rule #18), write base output, insert 4 keys.
#define CONSUME(t, slot, vm) do {                                            \
    asm volatile("s_waitcnt vmcnt(" #vm ")" ::: "memory");                   \
    __builtin_amdgcn_sched_barrier(0);                                       \
    const int col = (t) * 256 + lane4;                                       \
    vfloat4 ov = av##slot * 1e-7f;                                           \
    __builtin_nontemporal_store(ov, reinterpret_cast<vfloat4*>(orow + col)); \
    float s0, s1, s2, s3;                                                    \
    {                                                                        \
        _Pragma("clang fp contract(off)")                                    \
        s0 = fabsf(av##slot.x) + nv##slot.x * 0.01f;                         \
        s1 = fabsf(av##slot.y) + nv##slot.y * 0.01f;                         \
        s2 = fabsf(av##slot.z) + nv##slot.z * 0.01f;                         \
        s3 = fabsf(av##slot.w) + nv##slot.w * 0.01f;                         \
    }                                                                        \
    insert4(((u64)__float_as_uint(s0) << 32) | (unsigned)(NN - 1 - (col + 0)), m1, m2, m3, m4); \
    insert4(((u64)__float_as_uint(s1) << 32) | (unsigned)(NN - 1 - (col + 1)), m1, m2, m3, m4); \
    insert4(((u64)__float_as_uint(s2) << 32) | (unsigned)(NN - 1 - (col + 2)), m1, m2, m3, m4); \
    insert4(((u64)__float_as_uint(s3) << 32) | (unsigned)(NN - 1 - (col + 3)), m1, m2, m3, m4); \
} while (0)

// Kernel 1: one 64-lane wave per row. 3-slot ring software pipeline
// (prefetch distance 3, ~6 loads in flight/wave) + per-lane top-4 key cache
// (no sc[32] -> VGPR < 64 -> 8 waves/SIMD). Exact ordered top-20 per row
// (score desc, col asc on float-bit ties). Writes base out = adj*EPS (NT),
// winners[rg][rank] = col, adjhead[rg][0..19] = adj[rg][0..19].
__global__ __launch_bounds__(256, 8) void mask_topk_rows(
    const float* __restrict__ adj, const float* __restrict__ noise,
    float* __restrict__ out, unsigned short* __restrict__ winners,
    float* __restrict__ adjhead)
{
    const int lane  = threadIdx.x & 63;
    const int wave  = threadIdx.x >> 6;
    const int rg    = (blockIdx.x << 2) + wave;     // 0..16383
    const size_t base = (size_t)rg * NN;
    const float* __restrict__ arow = adj + base;
    const float* __restrict__ nrow = noise + base;
    float* __restrict__ orow = out + base;
    const int lane4 = lane << 2;

    vfloat4 av0, av1, av2, nv0, nv1, nv2;
    u64 m1 = 0, m2 = 0, m3 = 0, m4 = 0;

    // Prologue: 3 tile pairs in flight.
    ISSUE(0, 0); ISSUE(1, 1); ISSUE(2, 2);
    __builtin_amdgcn_sched_barrier(0);

    vfloat4 ahead;
    // Issue stream: L0L0'L1L1'L2L2' | Wt Ct(St) L(t+3)L(t+3)' ...
    // younger-than-pair-t counts: 4,5,6,6,6,6,4,2
    CONSUME(0, 0, 4); ahead = av0; ISSUE(0, 3);
    CONSUME(1, 1, 5); ISSUE(1, 4);
    CONSUME(2, 2, 6); ISSUE(2, 5);
    CONSUME(3, 0, 6); ISSUE(0, 6);
    CONSUME(4, 1, 6); ISSUE(1, 7);
    CONSUME(5, 2, 6);
    CONSUME(6, 0, 4);
    CONSUME(7, 1, 2);

    // ---- Exact ordered top-20 extraction from per-lane top-4 cache ----
    int cnt = 4;                 // valid entries in m1..m4
    unsigned int removed = 0;    // per-lane slot mask of extracted elements
    unsigned int mycol = 0;

    #pragma clang loop unroll(disable)
    for (int pass = 0; pass < KK; ++pass) {
        const int hs = (int)(unsigned int)(m1 >> 32);     // score bits (>=0)
        const int smax = wave_max_i32(hs);                // global max score
        const bool tied = (hs == smax);
        const unsigned long long ball = __ballot(tied);
        unsigned int col;
        bool iwin;
        if (__popcll(ball) == 1) {
            // fast path: unique score owner -- no tie-break reduce needed
            const int wl = __ffsll((long long)ball) - 1;  // SGPR-uniform lane
            const unsigned int wlo = (unsigned int)
                __builtin_amdgcn_readlane((int)(unsigned int)m1, wl);
            col = (NN - 1) - wlo;
            iwin = (lane == wl);
        } else {
            // exact tie on score bits across lanes: pick smallest col
            const int lo = tied ? (int)(unsigned int)m1 : 0;  // 2047-col
            const int tmax = wave_max_i32(lo);
            col = (NN - 1) - (unsigned int)tmax;
            iwin = tied && ((int)(unsigned int)m1 == tmax);
        }
        if (lane == pass) mycol = col;
        if (iwin) {
            removed |= 1u << (((col >> 8) << 2) | (col & 3));
            m1 = m2; m2 = m3; m3 = m4; m4 = 0ull;
            if (--cnt == 0) {
                // rare (~2% of rows, single lane): reload row (L3-hot) and
                // rebuild top-4 of non-removed elements. Must match numpy
                // bitwise -> same contract-off score computation.
                m1 = 0ull; m2 = 0ull; m3 = 0ull; m4 = 0ull;
                #pragma clang loop unroll(disable)
                for (int t2 = 0; t2 < 8; ++t2) {
                    const int c2 = t2 * 256 + lane4;
                    const float4 a2 = *reinterpret_cast<const float4*>(arow + c2);
                    const float4 n2 = *reinterpret_cast<const float4*>(nrow + c2);
                    float r0, r1, r2, r3;
                    {
                        #pragma clang fp contract(off)
                        r0 = fabsf(a2.x) + n2.x * 0.01f;
                        r1 = fabsf(a2.y) + n2.y * 0.01f;
                        r2 = fabsf(a2.z) + n2.z * 0.01f;
                        r3 = fabsf(a2.w) + n2.w * 0.01f;
                    }
                    if (!((removed >> (t2 * 4 + 0)) & 1u))
                        insert4(((u64)__float_as_uint(r0) << 32) | (unsigned)(NN - 1 - (c2 + 0)), m1, m2, m3, m4);
                    if (!((removed >> (t2 * 4 + 1)) & 1u))
                        insert4(((u64)__float_as_uint(r1) << 32) | (unsigned)(NN - 1 - (c2 + 1)), m1, m2, m3, m4);
                    if (!((removed >> (t2 * 4 + 2)) & 1u))
                        insert4(((u64)__float_as_uint(r2) << 32) | (unsigned)(NN - 1 - (c2 + 2)), m1, m2, m3, m4);
                    if (!((removed >> (t2 * 4 + 3)) & 1u))
                        insert4(((u64)__float_as_uint(r3) << 32) | (unsigned)(NN - 1 - (c2 + 3)), m1, m2, m3, m4);
                }
                cnt = 4;
            }
        }
    }

    if (lane < KK) {
        winners[(size_t)rg * KK + lane] = (unsigned short)mycol;
    }
    if (lane < 5) {
        // adjhead[rg][0..19]: lanes 0..4 hold cols 0..19 in ahead (tile 0).
        *reinterpret_cast<vfloat4*>(adjhead + (size_t)rg * KK + lane4) = ahead;
    }
}

// Kernel 2: for each (slice,row,rank): col = winners[...];
// out[slice][col][rank] = adjhead[slice*NN+col][rank]*(1+EPS).
// Duplicate (col,rank) targets write identical values -> benign race.
__global__ __launch_bounds__(256) void mask_boost(
    float* __restrict__ out, const unsigned short* __restrict__ winners,
    const float* __restrict__ adjhead)
{
    const int idx = blockIdx.x * 256 + threadIdx.x;
    if (idx >= NBOOST) return;
    const int rank  = idx % KK;
    const int slice = idx / (KK * NN);
    const int col = winners[idx];
    const size_t wrow = (size_t)slice * NN + col;
    const float v = adjhead[wrow * KK + rank];
    out[wrow * NN + rank] = v * (1.0f + 1e-7f);
}

extern "C" void kernel_launch(void* const* d_in, const int* in_sizes, int n_in,
                              void* d_out, int out_size, void* d_ws, size_t ws_size,
                              hipStream_t stream) {
    const float* adj   = (const float*)d_in[0];
    const float* noise = (const float*)d_in[1];
    float* out = (float*)d_out;
    unsigned short* winners = (unsigned short*)d_ws;            // 640 KiB
    float* adjhead = (float*)((char*)d_ws + (size_t)NROWS * KK * sizeof(unsigned short));
    // adjhead: 16384*20*4B = 1.25 MiB (total ws use < 2 MiB)

    mask_topk_rows<<<NROWS / 4, 256, 0, stream>>>(adj, noise, out, winners, adjhead);
    mask_boost<<<(NBOOST + 255) / 256, 256, 0, stream>>>(out, winners, adjhead);
}